// Round 8
// baseline (264.653 us; speedup 1.0000x reference)
//
#include <hip/hip_runtime.h>

typedef __bf16 bf16_t;
typedef __bf16 bf16x8 __attribute__((ext_vector_type(8)));
typedef __bf16 bf16x4v __attribute__((ext_vector_type(4)));
typedef __bf16 bf16x2v __attribute__((ext_vector_type(2)));
typedef float f32x4 __attribute__((ext_vector_type(4)));
typedef unsigned long long u64;

#define LN_EPS 1e-5f

// njuffa's 1-ulp erff (fast path for |a|<=0.921875 is 6 fma)
__device__ __forceinline__ float erf_fast(float a) {
  const float t = fabsf(a);
  const float s = a * a;
  float r;
  if (t > 0.921875f) {
    float u;
    r = fmaf(-1.72853470e-5f, t, 3.83197126e-4f);
    u = fmaf(-3.88396438e-3f, t, 2.42546219e-2f);
    r = fmaf(r, s, u);
    r = fmaf(r, t, 1.06777877e-1f);
    r = fmaf(r, t, -6.37245935e-1f);
    r = fmaf(r, t, -1.28717512e-1f);
    r = fmaf(r, t, t);
    r = 1.0f - __expf(-r);
    r = copysignf(r, a);
  } else {
    r = -5.96761703e-4f;
    r = fmaf(r, s, 4.99119423e-3f);
    r = fmaf(r, s, -2.67681349e-2f);
    r = fmaf(r, s, 1.12819925e-1f);
    r = fmaf(r, s, -3.76125336e-1f);
    r = fmaf(r, s, 1.28379166e-1f);
    r = fmaf(r, a, a);
  }
  return r;
}

__device__ __forceinline__ float gelu_f(float x) {
  const float h = 0.5f * x;
  return fmaf(h, erf_fast(x * 0.70710678118654752f), h);
}

__device__ __forceinline__ void async16(const bf16_t* g, bf16_t* l) {
  __builtin_amdgcn_global_load_lds(
      (const __attribute__((address_space(1))) void*)g,
      (__attribute__((address_space(3))) void*)l, 16, 0, 0);
}

// LDS k-chunk swizzle: physical 16B chunk = logical ^ ((row>>1)&3).
// Stores stay lane-linear (async16-legal); fragment ds_read_b128 spreads
// each quad over all 4 chunk positions -> 2-way bank aliasing only (free).
__device__ __forceinline__ int swz(int row, int p) { return p ^ ((row >> 1) & 3); }

// ---------------------------------------------------------------------------
// prep: X,S -> bf16 ; weights -> transposed bf16 ; zero bitmap+gatelin
// ---------------------------------------------------------------------------
__global__ __launch_bounds__(256)
void prep_kernel(const float* __restrict__ X, const float* __restrict__ S,
                 const float* __restrict__ Wg, const float* __restrict__ Wk,
                 const float* __restrict__ Wm1, const float* __restrict__ Wgt1,
                 const float* __restrict__ Wm2, const float* __restrict__ Wqkv,
                 const float* __restrict__ Wo, const float* __restrict__ Wu1,
                 const float* __restrict__ Wu2,
                 bf16_t* __restrict__ Xb, bf16_t* __restrict__ Sb,
                 bf16_t* __restrict__ W1t, bf16_t* __restrict__ W2t,
                 bf16_t* __restrict__ Wqkvt, bf16_t* __restrict__ Wot,
                 bf16_t* __restrict__ Wu1t, bf16_t* __restrict__ Wu2t,
                 float4* __restrict__ zbase)
{
  const int bid = blockIdx.x;
  const int t = threadIdx.x;
  if (bid < 8192) {                       // X
    const int i = bid * 256 + t;
    const float4 v = ((const float4*)X)[i];
    bf16x4v o; o[0]=(bf16_t)v.x; o[1]=(bf16_t)v.y; o[2]=(bf16_t)v.z; o[3]=(bf16_t)v.w;
    ((bf16x4v*)Xb)[i] = o;
  } else if (bid < 9216) {                // S
    const int i = (bid - 8192) * 256 + t;
    const float4 v = ((const float4*)S)[i];
    bf16x4v o; o[0]=(bf16_t)v.x; o[1]=(bf16_t)v.y; o[2]=(bf16_t)v.z; o[3]=(bf16_t)v.w;
    ((bf16x4v*)Sb)[i] = o;
  } else if (bid < 10112) {               // W1t: 896 rows x 256
    const int n = bid - 9216;
    const int k = t;
    float v;
    if (n < 512)      v = Wm1[k * 512 + n];
    else if (n < 768) v = Wgt1[k * 256 + (n - 512)];
    else if (n < 832) v = Wg[k * 64 + (n - 768)];
    else if (n < 840) v = Wk[k * 8 + (n - 832)];
    else              v = 0.f;
    W1t[n * 256 + k] = (bf16_t)v;
  } else if (bid < 10368) {               // W2t: 256 rows x 512
    const int n = bid - 10112;
    for (int k = t; k < 512; k += 256) W2t[n * 512 + k] = (bf16_t)Wm2[k * 256 + n];
  } else if (bid < 11136) {               // Wqkvt: 768 x 256
    const int n = bid - 10368;
    Wqkvt[n * 256 + t] = (bf16_t)Wqkv[t * 768 + n];
  } else if (bid < 11392) {               // Wot: 256 x 256
    const int n = bid - 11136;
    Wot[n * 256 + t] = (bf16_t)Wo[t * 256 + n];
  } else if (bid < 11904) {               // Wu1t: 512 x 512
    const int n = bid - 11392;
    for (int k = t; k < 512; k += 256) Wu1t[n * 512 + k] = (bf16_t)Wu1[k * 512 + n];
  } else if (bid < 12160) {               // Wu2t: 256 x 512
    const int n = bid - 11904;
    for (int k = t; k < 512; k += 256) Wu2t[n * 512 + k] = (bf16_t)Wu2[k * 256 + n];
  } else {                                // zero bitmap (2MB) + gatelin (128KB)
    zbase[(bid - 12160) * 256 + t] = make_float4(0.f, 0.f, 0.f, 0.f);
  }
}

// ---------------------------------------------------------------------------
// bf16 MFMA GEMM: C[M x N] = A[M x K] * Bt[N x K]^T, tile (MT*32) x 128, BK=32
// MFMA operands swapped: lane's 4 acc regs = 4 consecutive cols of one row.
// EPI 1 (G1R): by<4 -> v+bm1 RAW -> h1 (gelu deferred to gather)
//              by 4/5 -> gelu(+bgt1), dot with Wgt2 -> atomicAdd gatelin
//              by 6 -> argmax(Wg),argmax(Wk) -> bitmap atomicOr
// EPI 5: gelu(+bias) -> bf16
// ---------------------------------------------------------------------------
template<int MT, int EPI>
__global__ __launch_bounds__(256)
void gemm_kernel(const bf16_t* __restrict__ A, int lda,
                 const bf16_t* __restrict__ Bt, int K,
                 const float* __restrict__ bias, const float* __restrict__ bias2,
                 void* __restrict__ outp, int ldc,
                 const float* __restrict__ wgt2, float* __restrict__ gatelin,
                 u64* __restrict__ bitmap)
{
  constexpr int BM = MT * 32;
  constexpr int CA = BM * 4;             // 16B chunks per k-pass (A)
  const int m0 = blockIdx.x * BM;
  const int by = blockIdx.y;
  const int n0 = by * 128;
  const int t = threadIdx.x;
  const int w = t >> 6;
  const int lane = t & 63;
  const int wr = w >> 1, wc = w & 1;
  const int quad = lane >> 4, l15 = lane & 15;

  __shared__ bf16_t lA[BM * 32];
  __shared__ bf16_t lB[128 * 32];
  __shared__ float sWg[256];
  __shared__ int sKi[BM];

  if constexpr (EPI == 1) {
    if (by >= 4 && by < 6) sWg[t] = wgt2[t];
  }

  f32x4 acc[MT][4];
#pragma unroll
  for (int mt = 0; mt < MT; ++mt)
#pragma unroll
    for (int nt = 0; nt < 4; ++nt)
      acc[mt][nt] = (f32x4){0.f, 0.f, 0.f, 0.f};

  for (int k0 = 0; k0 < K; k0 += 32) {
    if constexpr (CA >= 256) {
#pragma unroll
      for (int i = 0; i < CA / 256; ++i) {
        const int c = i * 256 + t;
        const int row = c >> 2, pp = c & 3;
        async16(A + (size_t)(m0 + row) * lda + k0 + (swz(row, pp) << 3),
                lA + (size_t)(i * 256 + (t & 192)) * 8);
      }
    } else {
      if (t < CA) {
        const int row = t >> 2, pp = t & 3;
        async16(A + (size_t)(m0 + row) * lda + k0 + (swz(row, pp) << 3),
                lA + (size_t)(t & 192) * 8);
      }
    }
#pragma unroll
    for (int i = 0; i < 2; ++i) {
      const int c = i * 256 + t;
      const int row = c >> 2, pp = c & 3;
      async16(Bt + (size_t)(n0 + row) * K + k0 + (swz(row, pp) << 3),
              lB + (size_t)(i * 256 + (t & 192)) * 8);
    }
    __syncthreads();
    bf16x8 af[MT], bfr[4];
#pragma unroll
    for (int mt = 0; mt < MT; ++mt) {
      const int row = wr * MT * 16 + mt * 16 + l15;
      af[mt] = *(const bf16x8*)&lA[row * 32 + (swz(row, quad) << 3)];
    }
#pragma unroll
    for (int nt = 0; nt < 4; ++nt) {
      const int row = wc * 64 + nt * 16 + l15;
      bfr[nt] = *(const bf16x8*)&lB[row * 32 + (swz(row, quad) << 3)];
    }
#pragma unroll
    for (int mt = 0; mt < MT; ++mt)
#pragma unroll
      for (int nt = 0; nt < 4; ++nt)
        acc[mt][nt] = __builtin_amdgcn_mfma_f32_16x16x32_bf16(bfr[nt], af[mt], acc[mt][nt], 0, 0, 0);
    __syncthreads();
  }

  if constexpr (EPI == 1) {
    if (by < 4) {
      // msg: v + bm1 raw -> h1 bf16 (gelu applied in gather)
#pragma unroll
      for (int mt = 0; mt < MT; ++mt) {
        const int row = m0 + wr * MT * 16 + mt * 16 + l15;
#pragma unroll
        for (int nt = 0; nt < 4; ++nt) {
          const int colb = n0 + wc * 64 + nt * 16 + quad * 4;
          const float4 bb = *(const float4*)&bias[colb];
          bf16x4v o;
          o[0] = (bf16_t)(acc[mt][nt][0] + bb.x);
          o[1] = (bf16_t)(acc[mt][nt][1] + bb.y);
          o[2] = (bf16_t)(acc[mt][nt][2] + bb.z);
          o[3] = (bf16_t)(acc[mt][nt][3] + bb.w);
          *(bf16x4v*)&((bf16_t*)outp)[(size_t)row * 512 + colb] = o;
        }
      }
    } else if (by < 6) {
      // gate strips: partial dot of gelu(g1) with Wgt2 -> atomicAdd gatelin
#pragma unroll
      for (int mt = 0; mt < MT; ++mt) {
        const int row = m0 + wr * MT * 16 + mt * 16 + l15;
        float part = 0.f;
#pragma unroll
        for (int nt = 0; nt < 4; ++nt) {
          const int colb = n0 + wc * 64 + nt * 16 + quad * 4;
          const int c = colb - 512;
          const float4 bb = *(const float4*)&bias2[c];
          part = fmaf(gelu_f(acc[mt][nt][0] + bb.x), sWg[c + 0], part);
          part = fmaf(gelu_f(acc[mt][nt][1] + bb.y), sWg[c + 1], part);
          part = fmaf(gelu_f(acc[mt][nt][2] + bb.z), sWg[c + 2], part);
          part = fmaf(gelu_f(acc[mt][nt][3] + bb.w), sWg[c + 3], part);
        }
        part += __shfl_xor(part, 16, 64);
        part += __shfl_xor(part, 32, 64);
        if (lane < 16) atomicAdd(&gatelin[row], part);
      }
    } else {
      // logit strip: argmax(g)*8 + argmax(k) -> bitmap
      int bi[MT];
#pragma unroll
      for (int mt = 0; mt < MT; ++mt) {
        if (wc == 0) {
          float mv = -1e30f; int mi = 0;
#pragma unroll
          for (int nt = 0; nt < 4; ++nt)
#pragma unroll
            for (int j = 0; j < 4; ++j) {
              const int gc = nt * 16 + quad * 4 + j;
              const float v = acc[mt][nt][j];
              if (v > mv || (v == mv && gc < mi)) { mv = v; mi = gc; }
            }
#pragma unroll
          for (int off = 16; off <= 32; off <<= 1) {
            const float ov = __shfl_xor(mv, off, 64);
            const int oi = __shfl_xor(mi, off, 64);
            if (ov > mv || (ov == mv && oi < mi)) { mv = ov; mi = oi; }
          }
          bi[mt] = mi;
        } else {
          float mv = -1e30f; int mi = 0;
          if (quad < 2) {
#pragma unroll
            for (int j = 0; j < 4; ++j) {
              const int kc = quad * 4 + j;
              const float v = acc[mt][0][j];
              if (v > mv || (v == mv && kc < mi)) { mv = v; mi = kc; }
            }
          }
#pragma unroll
          for (int off = 16; off <= 32; off <<= 1) {
            const float ov = __shfl_xor(mv, off, 64);
            const int oi = __shfl_xor(mi, off, 64);
            if (ov > mv || (ov == mv && oi < mi)) { mv = ov; mi = oi; }
          }
          if (lane < 16) sKi[wr * MT * 16 + mt * 16 + l15] = mi;
        }
      }
      __syncthreads();
      if (wc == 0 && lane < 16) {
#pragma unroll
        for (int mt = 0; mt < MT; ++mt) {
          const int rl = wr * MT * 16 + mt * 16 + l15;
          const int row = m0 + rl;
          const int idx = bi[mt] * 8 + sKi[rl];
          const int b = row >> 12, tok = row & 4095;
          atomicOr(&bitmap[(size_t)(b * 512 + idx) * 64 + (tok >> 6)],
                   1ull << (tok & 63));
        }
      }
    }
  } else {  // EPI 5: gelu(+bias) -> bf16
#pragma unroll
    for (int mt = 0; mt < MT; ++mt) {
      const int row = m0 + wr * MT * 16 + mt * 16 + l15;
#pragma unroll
      for (int nt = 0; nt < 4; ++nt) {
        const int colb = n0 + wc * 64 + nt * 16 + quad * 4;
        const float4 bb = *(const float4*)&bias[colb];
        bf16x4v o;
        o[0]=(bf16_t)gelu_f(acc[mt][nt][0]+bb.x); o[1]=(bf16_t)gelu_f(acc[mt][nt][1]+bb.y);
        o[2]=(bf16_t)gelu_f(acc[mt][nt][2]+bb.z); o[3]=(bf16_t)gelu_f(acc[mt][nt][3]+bb.w);
        *(bf16x4v*)&((bf16_t*)outp)[(size_t)row * ldc + colb] = o;
      }
    }
  }
}

// ---------------------------------------------------------------------------
// pair: blocks [0,256) = G2' (incoming = H@Wm2 + sumg*bm2, f32)
//       blocks [256,1024) = qkv (Sb@Wqkvt + bqkv, bf16)
// ---------------------------------------------------------------------------
__global__ __launch_bounds__(256)
void gemm_pair_kernel(const bf16_t* __restrict__ H, const bf16_t* __restrict__ W2t,
                      const float* __restrict__ bm2, const float* __restrict__ sumg,
                      float* __restrict__ incom,
                      const bf16_t* __restrict__ Sb, const bf16_t* __restrict__ Wqkvt,
                      const float* __restrict__ bqkv, bf16_t* __restrict__ qkvb)
{
  int id = blockIdx.x;
  const bool first = id < 256;
  if (!first) id -= 256;
  const bf16_t* A  = first ? H : Sb;
  const bf16_t* Bt = first ? W2t : Wqkvt;
  const float* bias = first ? bm2 : bqkv;
  const int lda = first ? 512 : 256;
  const int K   = first ? 512 : 256;
  const int ldc = first ? 256 : 768;
  const int m0 = (id & 127) * 32;
  const int n0 = (id >> 7) * 128;
  const int t = threadIdx.x;
  const int w = t >> 6;
  const int lane = t & 63;
  const int wr = w >> 1, wc = w & 1;
  const int quad = lane >> 4, l15 = lane & 15;

  __shared__ bf16_t lA[32 * 32];
  __shared__ bf16_t lB[128 * 32];

  f32x4 acc[4];
#pragma unroll
  for (int nt = 0; nt < 4; ++nt) acc[nt] = (f32x4){0.f, 0.f, 0.f, 0.f};

  for (int k0 = 0; k0 < K; k0 += 32) {
    if (t < 128) {
      const int row = t >> 2, pp = t & 3;
      async16(A + (size_t)(m0 + row) * lda + k0 + (swz(row, pp) << 3),
              lA + (size_t)(t & 192) * 8);
    }
#pragma unroll
    for (int i = 0; i < 2; ++i) {
      const int c = i * 256 + t;
      const int row = c >> 2, pp = c & 3;
      async16(Bt + (size_t)(n0 + row) * K + k0 + (swz(row, pp) << 3),
              lB + (size_t)(i * 256 + (t & 192)) * 8);
    }
    __syncthreads();
    bf16x8 af, bfr[4];
    const int arow = wr * 16 + l15;
    af = *(const bf16x8*)&lA[arow * 32 + (swz(arow, quad) << 3)];
#pragma unroll
    for (int nt = 0; nt < 4; ++nt) {
      const int row = wc * 64 + nt * 16 + l15;
      bfr[nt] = *(const bf16x8*)&lB[row * 32 + (swz(row, quad) << 3)];
    }
#pragma unroll
    for (int nt = 0; nt < 4; ++nt)
      acc[nt] = __builtin_amdgcn_mfma_f32_16x16x32_bf16(bfr[nt], af, acc[nt], 0, 0, 0);
    __syncthreads();
  }

  const int row = m0 + wr * 16 + l15;
  if (first) {
    const float gt = sumg[row];
#pragma unroll
    for (int nt = 0; nt < 4; ++nt) {
      const int colb = n0 + wc * 64 + nt * 16 + quad * 4;
      const float4 bb = *(const float4*)&bias[colb];
      *(float4*)&incom[(size_t)row * ldc + colb] =
          make_float4(fmaf(gt, bb.x, acc[nt][0]), fmaf(gt, bb.y, acc[nt][1]),
                      fmaf(gt, bb.z, acc[nt][2]), fmaf(gt, bb.w, acc[nt][3]));
    }
  } else {
#pragma unroll
    for (int nt = 0; nt < 4; ++nt) {
      const int colb = n0 + wc * 64 + nt * 16 + quad * 4;
      const float4 bb = *(const float4*)&bias[colb];
      bf16x4v o; o[0]=(bf16_t)(acc[nt][0]+bb.x); o[1]=(bf16_t)(acc[nt][1]+bb.y);
      o[2]=(bf16_t)(acc[nt][2]+bb.z); o[3]=(bf16_t)(acc[nt][3]+bb.w);
      *(bf16x4v*)&qkvb[(size_t)row * ldc + colb] = o;
    }
  }
}

// ---------------------------------------------------------------------------
// gather: block per (b,slot); bitmap-driven; H = sum gate*gelu(h1) rows; sumg
// ---------------------------------------------------------------------------
__global__ __launch_bounds__(256)
void gather_kernel(const bf16_t* __restrict__ h1, const float* __restrict__ gatelin,
                   const float* __restrict__ bgt2, const u64* __restrict__ bitmap,
                   bf16_t* __restrict__ H, float* __restrict__ sumg)
{
  const int bs = blockIdx.x;
  const int b = bs >> 9;
  const int t = threadIdx.x;
  __shared__ u64 sw[64];
  if (t < 64) sw[t] = bitmap[(size_t)bs * 64 + t];
  __syncthreads();
  const float bg = bgt2[0];
  float a0 = 0.f, a1 = 0.f, sg = 0.f;
  for (int wd = 0; wd < 64; ++wd) {
    u64 word = sw[wd];
    while (word) {
      const int bit = __builtin_ctzll(word);
      word &= word - 1;
      const int l = (b << 12) + (wd << 6) + bit;
      const float g = 1.0f / (1.0f + __expf(-(gatelin[l] + bg)));
      const bf16x2v hv = *(const bf16x2v*)&h1[(size_t)l * 512 + t * 2];
      a0 = fmaf(g, gelu_f((float)hv[0]), a0);
      a1 = fmaf(g, gelu_f((float)hv[1]), a1);
      sg += g;
    }
  }
  bf16x2v o; o[0] = (bf16_t)a0; o[1] = (bf16_t)a1;
  *(bf16x2v*)&H[(size_t)bs * 512 + t * 2] = o;
  if (t == 0) sumg[bs] = sg;
}

// ---------------------------------------------------------------------------
// fused slot attention: block = (b, h, 32-query chunk)
// ---------------------------------------------------------------------------
__global__ __launch_bounds__(256)
void attn_kernel(const bf16_t* __restrict__ qkv, bf16_t* __restrict__ obuf)
{
  const int bid = blockIdx.x;
  const int qc = bid & 15;
  const int h = (bid >> 4) & 7;
  const int b = bid >> 7;
  const int t = threadIdx.x;
  const int w = t >> 6, lane = t & 63;
  const int quad = lane >> 4, l15 = lane & 15;

  __shared__ bf16_t sP[32 * 520];
  __shared__ bf16_t sVt[32 * 264];
  __shared__ float sL[32];

  bf16x8 qf[2];
#pragma unroll
  for (int mt = 0; mt < 2; ++mt) {
    const int row = b * 512 + qc * 32 + mt * 16 + l15;
    qf[mt] = *(const bf16x8*)&qkv[(size_t)row * 768 + h * 32 + quad * 8];
  }
  const float scale = 0.17677669529663687f;  // 1/sqrt(32)
  for (int kt = w; kt < 32; kt += 4) {
    const int key = b * 512 + kt * 16 + l15;
    const bf16x8 kf = *(const bf16x8*)&qkv[(size_t)key * 768 + 256 + h * 32 + quad * 8];
#pragma unroll
    for (int mt = 0; mt < 2; ++mt) {
      f32x4 c = (f32x4){0.f, 0.f, 0.f, 0.f};
      c = __builtin_amdgcn_mfma_f32_16x16x32_bf16(qf[mt], kf, c, 0, 0, 0);
#pragma unroll
      for (int r = 0; r < 4; ++r)
        sP[(mt * 16 + quad * 4 + r) * 520 + kt * 16 + l15] = (bf16_t)(c[r] * scale);
    }
  }
  __syncthreads();

#pragma unroll
  for (int ri = 0; ri < 8; ++ri) {
    const int row = w * 8 + ri;
    const bf16x8 sv = *(const bf16x8*)&sP[row * 520 + lane * 8];
    float sval[8];
    float mx = -1e30f;
#pragma unroll
    for (int j = 0; j < 8; ++j) { sval[j] = (float)sv[j]; mx = fmaxf(mx, sval[j]); }
#pragma unroll
    for (int off = 32; off; off >>= 1) mx = fmaxf(mx, __shfl_xor(mx, off, 64));
    float sum = 0.f;
    bf16x8 pv;
#pragma unroll
    for (int j = 0; j < 8; ++j) { const float e = __expf(sval[j] - mx); sum += e; pv[j] = (bf16_t)e; }
#pragma unroll
    for (int off = 32; off; off >>= 1) sum += __shfl_xor(sum, off, 64);
    *(bf16x8*)&sP[row * 520 + lane * 8] = pv;
    if (lane == 0) sL[row] = sum;
  }
  __syncthreads();

  const int omt = w >> 1, ont = w & 1;
  f32x4 oacc = (f32x4){0.f, 0.f, 0.f, 0.f};
  for (int half = 0; half < 2; ++half) {
    if (half) __syncthreads();
#pragma unroll
    for (int i = 0; i < 32; ++i) {
      const int el = i * 256 + t;
      const int dh = el & 31, key = el >> 5;
      sVt[dh * 264 + key] = qkv[(size_t)(b * 512 + half * 256 + key) * 768 + 512 + h * 32 + dh];
    }
    __syncthreads();
#pragma unroll
    for (int kt = 0; kt < 8; ++kt) {
      const bf16x8 af = *(const bf16x8*)&sP[(omt * 16 + l15) * 520 + half * 256 + kt * 32 + quad * 8];
      const bf16x8 vf = *(const bf16x8*)&sVt[(ont * 16 + l15) * 264 + kt * 32 + quad * 8];
      oacc = __builtin_amdgcn_mfma_f32_16x16x32_bf16(af, vf, oacc, 0, 0, 0);
    }
  }
#pragma unroll
  for (int r = 0; r < 4; ++r) {
    const int row = omt * 16 + quad * 4 + r;
    const float val = oacc[r] / sL[row];
    obuf[(size_t)(b * 512 + qc * 32 + row) * 256 + h * 32 + ont * 16 + l15] = (bf16_t)val;
  }
}

// ---------------------------------------------------------------------------
// wo_ln1: o2 = obuf@Wot + bo ; S1 = LN(S + o2) ; S1f f32 ; A4 = [S1|incom] bf16
// ---------------------------------------------------------------------------
__global__ __launch_bounds__(256)
void wo_ln1_kernel(const bf16_t* __restrict__ obuf, const bf16_t* __restrict__ Wot,
                   const float* __restrict__ bo, const float* __restrict__ S,
                   const float* __restrict__ incom, const float* __restrict__ g,
                   const float* __restrict__ bb, float* __restrict__ S1f,
                   bf16_t* __restrict__ A4)
{
  const int m0 = blockIdx.x * 16;
  const int t = threadIdx.x;
  const int w = t >> 6, lane = t & 63;
  const int quad = lane >> 4, l15 = lane & 15;

  __shared__ bf16_t lA[16 * 32];
  __shared__ bf16_t lB[256 * 32];
  __shared__ float sSum[4][16];
  __shared__ float sSq[4][16];

  f32x4 acc[4];
#pragma unroll
  for (int nt = 0; nt < 4; ++nt) acc[nt] = (f32x4){0.f, 0.f, 0.f, 0.f};

  for (int k0 = 0; k0 < 256; k0 += 32) {
    if (t < 64) {
      const int row = t >> 2, pp = t & 3;
      async16(obuf + (size_t)(m0 + row) * 256 + k0 + (swz(row, pp) << 3), lA);
    }
#pragma unroll
    for (int i = 0; i < 4; ++i) {
      const int c = i * 256 + t;
      const int row = c >> 2, pp = c & 3;
      async16(Wot + (size_t)row * 256 + k0 + (swz(row, pp) << 3),
              lB + (size_t)(i * 256 + (t & 192)) * 8);
    }
    __syncthreads();
    const bf16x8 af = *(const bf16x8*)&lA[l15 * 32 + (swz(l15, quad) << 3)];
#pragma unroll
    for (int nt = 0; nt < 4; ++nt) {
      const int row = w * 64 + nt * 16 + l15;
      const bf16x8 bfr = *(const bf16x8*)&lB[row * 32 + (swz(row, quad) << 3)];
      acc[nt] = __builtin_amdgcn_mfma_f32_16x16x32_bf16(bfr, af, acc[nt], 0, 0, 0);
    }
    __syncthreads();
  }

  const int row = m0 + l15;
  float sum = 0.f, sq = 0.f;
#pragma unroll
  for (int nt = 0; nt < 4; ++nt) {
    const int colb = w * 64 + nt * 16 + quad * 4;
    const float4 bv = *(const float4*)&bo[colb];
    const float4 sv = *(const float4*)&S[(size_t)row * 256 + colb];
    float x0 = acc[nt][0] + bv.x + sv.x, x1 = acc[nt][1] + bv.y + sv.y;
    float x2 = acc[nt][2] + bv.z + sv.z, x3 = acc[nt][3] + bv.w + sv.w;
    acc[nt][0] = x0; acc[nt][1] = x1; acc[nt][2] = x2; acc[nt][3] = x3;
    sum += x0 + x1 + x2 + x3;
    sq += x0*x0 + x1*x1 + x2*x2 + x3*x3;
  }
  sum += __shfl_xor(sum, 16, 64); sum += __shfl_xor(sum, 32, 64);
  sq  += __shfl_xor(sq, 16, 64);  sq  += __shfl_xor(sq, 32, 64);
  if (lane < 16) { sSum[w][l15] = sum; sSq[w][l15] = sq; }
  __syncthreads();
  const float tot = sSum[0][l15] + sSum[1][l15] + sSum[2][l15] + sSum[3][l15];
  const float tq  = sSq[0][l15] + sSq[1][l15] + sSq[2][l15] + sSq[3][l15];
  const float mean = tot * 0.00390625f;
  const float var = tq * 0.00390625f - mean * mean;
  const float rstd = rsqrtf(var + LN_EPS);
#pragma unroll
  for (int nt = 0; nt < 4; ++nt) {
    const int colb = w * 64 + nt * 16 + quad * 4;
    const float4 gg = *(const float4*)&g[colb];
    const float4 bv = *(const float4*)&bb[colb];
    const float y0 = (acc[nt][0]-mean)*rstd*gg.x + bv.x;
    const float y1 = (acc[nt][1]-mean)*rstd*gg.y + bv.y;
    const float y2 = (acc[nt][2]-mean)*rstd*gg.z + bv.z;
    const float y3 = (acc[nt][3]-mean)*rstd*gg.w + bv.w;
    *(float4*)&S1f[(size_t)row * 256 + colb] = make_float4(y0, y1, y2, y3);
    bf16x4v yb; yb[0]=(bf16_t)y0; yb[1]=(bf16_t)y1; yb[2]=(bf16_t)y2; yb[3]=(bf16_t)y3;
    *(bf16x4v*)&A4[(size_t)row * 512 + colb] = yb;
    const float4 ic = *(const float4*)&incom[(size_t)row * 256 + colb];
    bf16x4v ib; ib[0]=(bf16_t)ic.x; ib[1]=(bf16_t)ic.y; ib[2]=(bf16_t)ic.z; ib[3]=(bf16_t)ic.w;
    *(bf16x4v*)&A4[(size_t)row * 512 + 256 + colb] = ib;
  }
}

// ---------------------------------------------------------------------------
// wu2_ln2: S2 = U@Wu2t + bu2 + S1f ; out = LN(S2)  (final output, f32)
// ---------------------------------------------------------------------------
__global__ __launch_bounds__(256)
void wu2_ln2_kernel(const bf16_t* __restrict__ U, const bf16_t* __restrict__ Wu2t,
                    const float* __restrict__ bu2, const float* __restrict__ S1f,
                    const float* __restrict__ g, const float* __restrict__ bb,
                    float* __restrict__ out)
{
  const int m0 = blockIdx.x * 16;
  const int t = threadIdx.x;
  const int w = t >> 6, lane = t & 63;
  const int quad = lane >> 4, l15 = lane & 15;

  __shared__ bf16_t lA[16 * 32];
  __shared__ bf16_t lB[256 * 32];
  __shared__ float sSum[4][16];
  __shared__ float sSq[4][16];

  f32x4 acc[4];
#pragma unroll
  for (int nt = 0; nt < 4; ++nt) acc[nt] = (f32x4){0.f, 0.f, 0.f, 0.f};

  for (int k0 = 0; k0 < 512; k0 += 32) {
    if (t < 64) {
      const int row = t >> 2, pp = t & 3;
      async16(U + (size_t)(m0 + row) * 512 + k0 + (swz(row, pp) << 3), lA);
    }
#pragma unroll
    for (int i = 0; i < 4; ++i) {
      const int c = i * 256 + t;
      const int row = c >> 2, pp = c & 3;
      async16(Wu2t + (size_t)row * 512 + k0 + (swz(row, pp) << 3),
              lB + (size_t)(i * 256 + (t & 192)) * 8);
    }
    __syncthreads();
    const bf16x8 af = *(const bf16x8*)&lA[l15 * 32 + (swz(l15, quad) << 3)];
#pragma unroll
    for (int nt = 0; nt < 4; ++nt) {
      const int row = w * 64 + nt * 16 + l15;
      const bf16x8 bfr = *(const bf16x8*)&lB[row * 32 + (swz(row, quad) << 3)];
      acc[nt] = __builtin_amdgcn_mfma_f32_16x16x32_bf16(bfr, af, acc[nt], 0, 0, 0);
    }
    __syncthreads();
  }

  const int row = m0 + l15;
  float sum = 0.f, sq = 0.f;
#pragma unroll
  for (int nt = 0; nt < 4; ++nt) {
    const int colb = w * 64 + nt * 16 + quad * 4;
    const float4 bv = *(const float4*)&bu2[colb];
    const float4 sv = *(const float4*)&S1f[(size_t)row * 256 + colb];
    float x0 = acc[nt][0] + bv.x + sv.x, x1 = acc[nt][1] + bv.y + sv.y;
    float x2 = acc[nt][2] + bv.z + sv.z, x3 = acc[nt][3] + bv.w + sv.w;
    acc[nt][0] = x0; acc[nt][1] = x1; acc[nt][2] = x2; acc[nt][3] = x3;
    sum += x0 + x1 + x2 + x3;
    sq += x0*x0 + x1*x1 + x2*x2 + x3*x3;
  }
  sum += __shfl_xor(sum, 16, 64); sum += __shfl_xor(sum, 32, 64);
  sq  += __shfl_xor(sq, 16, 64);  sq  += __shfl_xor(sq, 32, 64);
  if (lane < 16) { sSum[w][l15] = sum; sSq[w][l15] = sq; }
  __syncthreads();
  const float tot = sSum[0][l15] + sSum[1][l15] + sSum[2][l15] + sSum[3][l15];
  const float tq  = sSq[0][l15] + sSq[1][l15] + sSq[2][l15] + sSq[3][l15];
  const float mean = tot * 0.00390625f;
  const float var = tq * 0.00390625f - mean * mean;
  const float rstd = rsqrtf(var + LN_EPS);
#pragma unroll
  for (int nt = 0; nt < 4; ++nt) {
    const int colb = w * 64 + nt * 16 + quad * 4;
    const float4 gg = *(const float4*)&g[colb];
    const float4 bv = *(const float4*)&bb[colb];
    *(float4*)&out[(size_t)row * 256 + colb] = make_float4(
        (acc[nt][0]-mean)*rstd*gg.x + bv.x, (acc[nt][1]-mean)*rstd*gg.y + bv.y,
        (acc[nt][2]-mean)*rstd*gg.z + bv.z, (acc[nt][3]-mean)*rstd*gg.w + bv.w);
  }
}

// ---------------------------------------------------------------------------
extern "C" void kernel_launch(void* const* d_in, const int* in_sizes, int n_in,
                              void* d_out, int out_size, void* d_ws, size_t ws_size,
                              hipStream_t stream)
{
  (void)in_sizes; (void)n_in; (void)out_size; (void)ws_size;
  const float* X    = (const float*)d_in[0];
  const float* S    = (const float*)d_in[1];
  const float* Wg   = (const float*)d_in[2];
  const float* Wk   = (const float*)d_in[3];
  const float* Wm1  = (const float*)d_in[4];
  const float* bm1  = (const float*)d_in[5];
  const float* Wm2  = (const float*)d_in[6];
  const float* bm2  = (const float*)d_in[7];
  const float* Wgt1 = (const float*)d_in[8];
  const float* bgt1 = (const float*)d_in[9];
  const float* Wgt2 = (const float*)d_in[10];
  const float* bgt2 = (const float*)d_in[11];
  const float* Wqkv = (const float*)d_in[12];
  const float* bqkv = (const float*)d_in[13];
  const float* Wo   = (const float*)d_in[14];
  const float* bo   = (const float*)d_in[15];
  const float* alng = (const float*)d_in[16];
  const float* alnb = (const float*)d_in[17];
  const float* Wu1  = (const float*)d_in[18];
  const float* bu1  = (const float*)d_in[19];
  const float* Wu2  = (const float*)d_in[20];
  const float* bu2  = (const float*)d_in[21];
  const float* lng  = (const float*)d_in[22];
  const float* lnb  = (const float*)d_in[23];

  char* p = (char*)d_ws;
  auto carve = [&](size_t bytes) { char* r = p; p += bytes; return r; };
  bf16_t* Xb    = (bf16_t*)carve(16777216);   // 32768 x 256
  bf16_t* Sb    = (bf16_t*)carve(2097152);    // 4096 x 256
  bf16_t* W1t   = (bf16_t*)carve(458752);     // 896 x 256
  bf16_t* W2t   = (bf16_t*)carve(262144);     // 256 x 512
  bf16_t* Wqkvt = (bf16_t*)carve(393216);     // 768 x 256
  bf16_t* Wot   = (bf16_t*)carve(131072);     // 256 x 256
  bf16_t* Wu1t  = (bf16_t*)carve(524288);     // 512 x 512
  bf16_t* Wu2t  = (bf16_t*)carve(262144);     // 256 x 512
  bf16_t* h1    = (bf16_t*)carve(33554432);   // 32768 x 512 (raw msg pre-act)
  u64*    bitmap  = (u64*)carve(2097152);     // 4096 slots x 64 words (zeroed by prep)
  float*  gatelin = (float*)carve(131072);    // 32768 (zeroed by prep, adjacent)
  float*  incom = (float*)carve(4194304);     // 4096 x 256 f32
  bf16_t* qkvb  = (bf16_t*)carve(6291456);    // 4096 x 768
  bf16_t* obuf  = (bf16_t*)carve(2097152);    // 4096 x 256
  float*  S1f   = (float*)carve(4194304);
  bf16_t* A4    = (bf16_t*)carve(4194304);    // 4096 x 512
  bf16_t* U     = (bf16_t*)carve(4194304);    // 4096 x 512 (aliased by H)
  float*  sumg  = (float*)carve(16384);
  bf16_t* H = U;  // disjoint lifetime: H dead before U written

  // 1. prep (+ zero bitmap & gatelin: 2228224 B = 544 blocks x 4 KB)
  prep_kernel<<<12704, 256, 0, stream>>>(X, S, Wg, Wk, Wm1, Wgt1, Wm2, Wqkv, Wo, Wu1, Wu2,
                                         Xb, Sb, W1t, W2t, Wqkvt, Wot, Wu1t, Wu2t,
                                         (float4*)bitmap);
  // 2. G1 + fused routing (BM=64)
  gemm_kernel<2,1><<<dim3(512,7), 256, 0, stream>>>(Xb, 256, W1t, 256, bm1, bgt1, h1, 512,
                                                    Wgt2, gatelin, bitmap);
  // 3. bitmap-driven aggregate (applies gelu)
  gather_kernel<<<4096, 256, 0, stream>>>(h1, gatelin, bgt2, bitmap, H, sumg);
  // 4. G2' (incoming) + qkv in one dispatch
  gemm_pair_kernel<<<1024, 256, 0, stream>>>(H, W2t, bm2, sumg, incom,
                                             Sb, Wqkvt, bqkv, qkvb);
  // 5. attention
  attn_kernel<<<1024, 256, 0, stream>>>(qkvb, obuf);
  // 6. Wo GEMM + LN1 + pack (fused)
  wo_ln1_kernel<<<256, 256, 0, stream>>>(obuf, Wot, bo, S, incom, alng, alnb, S1f, A4);
  // 7. update MLP hidden
  gemm_kernel<1,5><<<dim3(128,4), 256, 0, stream>>>(A4, 512, Wu1t, 512, bu1, nullptr, U, 512,
                                                    nullptr, nullptr, nullptr);
  // 8. update MLP out + residual + LN2 (fused) -> d_out
  wu2_ln2_kernel<<<256, 256, 0, stream>>>(U, Wu2t, bu2, S1f, lng, lnb, (float*)d_out);
}

// Round 9
// 263.372 us; speedup vs baseline: 1.0049x; 1.0049x over previous
//
#include <hip/hip_runtime.h>

typedef __bf16 bf16_t;
typedef __bf16 bf16x8 __attribute__((ext_vector_type(8)));
typedef __bf16 bf16x4v __attribute__((ext_vector_type(4)));
typedef __bf16 bf16x2v __attribute__((ext_vector_type(2)));
typedef float f32x4 __attribute__((ext_vector_type(4)));
typedef unsigned long long u64;

#define LN_EPS 1e-5f

// njuffa's 1-ulp erff (fast path for |a|<=0.921875 is 6 fma)
__device__ __forceinline__ float erf_fast(float a) {
  const float t = fabsf(a);
  const float s = a * a;
  float r;
  if (t > 0.921875f) {
    float u;
    r = fmaf(-1.72853470e-5f, t, 3.83197126e-4f);
    u = fmaf(-3.88396438e-3f, t, 2.42546219e-2f);
    r = fmaf(r, s, u);
    r = fmaf(r, t, 1.06777877e-1f);
    r = fmaf(r, t, -6.37245935e-1f);
    r = fmaf(r, t, -1.28717512e-1f);
    r = fmaf(r, t, t);
    r = 1.0f - __expf(-r);
    r = copysignf(r, a);
  } else {
    r = -5.96761703e-4f;
    r = fmaf(r, s, 4.99119423e-3f);
    r = fmaf(r, s, -2.67681349e-2f);
    r = fmaf(r, s, 1.12819925e-1f);
    r = fmaf(r, s, -3.76125336e-1f);
    r = fmaf(r, s, 1.28379166e-1f);
    r = fmaf(r, a, a);
  }
  return r;
}

__device__ __forceinline__ float gelu_f(float x) {
  const float h = 0.5f * x;
  return fmaf(h, erf_fast(x * 0.70710678118654752f), h);
}

__device__ __forceinline__ void async16(const bf16_t* g, bf16_t* l) {
  __builtin_amdgcn_global_load_lds(
      (const __attribute__((address_space(1))) void*)g,
      (__attribute__((address_space(3))) void*)l, 16, 0, 0);
}

// LDS k-chunk swizzle: physical 16B chunk = logical ^ ((row>>1)&3).
__device__ __forceinline__ int swz(int row, int p) { return p ^ ((row >> 1) & 3); }

// ---------------------------------------------------------------------------
// prep: X,S -> bf16 ; weights -> transposed bf16 via coalesced LDS 64x64 tiles
// ; zero bitmap+gatelin
// block map: [0,8192) X | [8192,9216) S | [9216,9248) Wm1 | [9248,9264) Wgt1
// | [9264,9268) Wg | 9268 Wk+zerofill | [9269,9301) Wm2 | [9301,9349) Wqkv
// | [9349,9365) Wo | [9365,9429) Wu1 | [9429,9461) Wu2 | [9461,10005) zero
// ---------------------------------------------------------------------------
__global__ __launch_bounds__(256)
void prep_kernel(const float* __restrict__ X, const float* __restrict__ S,
                 const float* __restrict__ Wg, const float* __restrict__ Wk,
                 const float* __restrict__ Wm1, const float* __restrict__ Wgt1,
                 const float* __restrict__ Wm2, const float* __restrict__ Wqkv,
                 const float* __restrict__ Wo, const float* __restrict__ Wu1,
                 const float* __restrict__ Wu2,
                 bf16_t* __restrict__ Xb, bf16_t* __restrict__ Sb,
                 bf16_t* __restrict__ W1t, bf16_t* __restrict__ W2t,
                 bf16_t* __restrict__ Wqkvt, bf16_t* __restrict__ Wot,
                 bf16_t* __restrict__ Wu1t, bf16_t* __restrict__ Wu2t,
                 float4* __restrict__ zbase)
{
  const int bid = blockIdx.x;
  const int t = threadIdx.x;
  __shared__ float sT[64][65];

  auto do_tr = [&](const float* src, int C, bf16_t* dst, int ld, int tiles_c, int j) {
    const int r0 = (j / tiles_c) * 64, c0 = (j % tiles_c) * 64;
#pragma unroll 4
    for (int i = 0; i < 16; ++i) {
      const int rr = i * 4 + (t >> 6), cc = t & 63;
      sT[rr][cc] = src[(size_t)(r0 + rr) * C + c0 + cc];
    }
    __syncthreads();
#pragma unroll 4
    for (int i = 0; i < 16; ++i) {
      const int rr = i * 4 + (t >> 6), cc = t & 63;
      dst[(size_t)(c0 + rr) * ld + r0 + cc] = (bf16_t)sT[cc][rr];
    }
  };

  if (bid < 8192) {                       // X
    const int i = bid * 256 + t;
    const float4 v = ((const float4*)X)[i];
    bf16x4v o; o[0]=(bf16_t)v.x; o[1]=(bf16_t)v.y; o[2]=(bf16_t)v.z; o[3]=(bf16_t)v.w;
    ((bf16x4v*)Xb)[i] = o;
  } else if (bid < 9216) {                // S
    const int i = (bid - 8192) * 256 + t;
    const float4 v = ((const float4*)S)[i];
    bf16x4v o; o[0]=(bf16_t)v.x; o[1]=(bf16_t)v.y; o[2]=(bf16_t)v.z; o[3]=(bf16_t)v.w;
    ((bf16x4v*)Sb)[i] = o;
  } else if (bid < 9248) {                // Wm1 256x512 -> W1t rows 0..511
    do_tr(Wm1, 512, W1t, 256, 8, bid - 9216);
  } else if (bid < 9264) {                // Wgt1 256x256 -> W1t rows 512..767
    do_tr(Wgt1, 256, W1t + 512 * 256, 256, 4, bid - 9248);
  } else if (bid < 9268) {                // Wg 256x64 -> W1t rows 768..831
    do_tr(Wg, 64, W1t + 768 * 256, 256, 1, bid - 9264);
  } else if (bid < 9269) {                // Wk 256x8 -> rows 832..839 ; zero 840..895
#pragma unroll
    for (int i = 0; i < 8; ++i)
      W1t[(832 + i) * 256 + t] = (bf16_t)Wk[t * 8 + i];
    for (int r = 0; r < 56; ++r)
      W1t[(840 + r) * 256 + t] = (bf16_t)0.f;
  } else if (bid < 9301) {                // Wm2 512x256 -> W2t
    do_tr(Wm2, 256, W2t, 512, 4, bid - 9269);
  } else if (bid < 9349) {                // Wqkv 256x768 -> Wqkvt
    do_tr(Wqkv, 768, Wqkvt, 256, 12, bid - 9301);
  } else if (bid < 9365) {                // Wo 256x256 -> Wot
    do_tr(Wo, 256, Wot, 256, 4, bid - 9349);
  } else if (bid < 9429) {                // Wu1 512x512 -> Wu1t
    do_tr(Wu1, 512, Wu1t, 512, 8, bid - 9365);
  } else if (bid < 9461) {                // Wu2 512x256 -> Wu2t
    do_tr(Wu2, 256, Wu2t, 512, 4, bid - 9429);
  } else {                                // zero bitmap (2MB) + gatelin (128KB)
    zbase[(bid - 9461) * 256 + t] = make_float4(0.f, 0.f, 0.f, 0.f);
  }
}

// ---------------------------------------------------------------------------
// G1R: C[M x 896] = Xb * W1t^T, tile 64x128, BK=32, fused routing epilogue
// ---------------------------------------------------------------------------
template<int MT, int EPI>
__global__ __launch_bounds__(256)
void gemm_kernel(const bf16_t* __restrict__ A, int lda,
                 const bf16_t* __restrict__ Bt, int K,
                 const float* __restrict__ bias, const float* __restrict__ bias2,
                 void* __restrict__ outp, int ldc,
                 const float* __restrict__ wgt2, float* __restrict__ gatelin,
                 u64* __restrict__ bitmap)
{
  constexpr int BM = MT * 32;
  constexpr int CA = BM * 4;
  const int m0 = blockIdx.x * BM;
  const int by = blockIdx.y;
  const int n0 = by * 128;
  const int t = threadIdx.x;
  const int w = t >> 6;
  const int lane = t & 63;
  const int wr = w >> 1, wc = w & 1;
  const int quad = lane >> 4, l15 = lane & 15;

  __shared__ bf16_t lA[BM * 32];
  __shared__ bf16_t lB[128 * 32];
  __shared__ float sWg[256];
  __shared__ int sKi[BM];

  if constexpr (EPI == 1) {
    if (by >= 4 && by < 6) sWg[t] = wgt2[t];
  }

  f32x4 acc[MT][4];
#pragma unroll
  for (int mt = 0; mt < MT; ++mt)
#pragma unroll
    for (int nt = 0; nt < 4; ++nt)
      acc[mt][nt] = (f32x4){0.f, 0.f, 0.f, 0.f};

  for (int k0 = 0; k0 < K; k0 += 32) {
    if constexpr (CA >= 256) {
#pragma unroll
      for (int i = 0; i < CA / 256; ++i) {
        const int c = i * 256 + t;
        const int row = c >> 2, pp = c & 3;
        async16(A + (size_t)(m0 + row) * lda + k0 + (swz(row, pp) << 3),
                lA + (size_t)(i * 256 + (t & 192)) * 8);
      }
    } else {
      if (t < CA) {
        const int row = t >> 2, pp = t & 3;
        async16(A + (size_t)(m0 + row) * lda + k0 + (swz(row, pp) << 3),
                lA + (size_t)(t & 192) * 8);
      }
    }
#pragma unroll
    for (int i = 0; i < 2; ++i) {
      const int c = i * 256 + t;
      const int row = c >> 2, pp = c & 3;
      async16(Bt + (size_t)(n0 + row) * K + k0 + (swz(row, pp) << 3),
              lB + (size_t)(i * 256 + (t & 192)) * 8);
    }
    __syncthreads();
    bf16x8 af[MT], bfr[4];
#pragma unroll
    for (int mt = 0; mt < MT; ++mt) {
      const int row = wr * MT * 16 + mt * 16 + l15;
      af[mt] = *(const bf16x8*)&lA[row * 32 + (swz(row, quad) << 3)];
    }
#pragma unroll
    for (int nt = 0; nt < 4; ++nt) {
      const int row = wc * 64 + nt * 16 + l15;
      bfr[nt] = *(const bf16x8*)&lB[row * 32 + (swz(row, quad) << 3)];
    }
#pragma unroll
    for (int mt = 0; mt < MT; ++mt)
#pragma unroll
      for (int nt = 0; nt < 4; ++nt)
        acc[mt][nt] = __builtin_amdgcn_mfma_f32_16x16x32_bf16(bfr[nt], af[mt], acc[mt][nt], 0, 0, 0);
    __syncthreads();
  }

  if constexpr (EPI == 1) {
    if (by < 4) {
#pragma unroll
      for (int mt = 0; mt < MT; ++mt) {
        const int row = m0 + wr * MT * 16 + mt * 16 + l15;
#pragma unroll
        for (int nt = 0; nt < 4; ++nt) {
          const int colb = n0 + wc * 64 + nt * 16 + quad * 4;
          const float4 bb = *(const float4*)&bias[colb];
          bf16x4v o;
          o[0] = (bf16_t)(acc[mt][nt][0] + bb.x);
          o[1] = (bf16_t)(acc[mt][nt][1] + bb.y);
          o[2] = (bf16_t)(acc[mt][nt][2] + bb.z);
          o[3] = (bf16_t)(acc[mt][nt][3] + bb.w);
          *(bf16x4v*)&((bf16_t*)outp)[(size_t)row * 512 + colb] = o;
        }
      }
    } else if (by < 6) {
#pragma unroll
      for (int mt = 0; mt < MT; ++mt) {
        const int row = m0 + wr * MT * 16 + mt * 16 + l15;
        float part = 0.f;
#pragma unroll
        for (int nt = 0; nt < 4; ++nt) {
          const int colb = n0 + wc * 64 + nt * 16 + quad * 4;
          const int c = colb - 512;
          const float4 bb = *(const float4*)&bias2[c];
          part = fmaf(gelu_f(acc[mt][nt][0] + bb.x), sWg[c + 0], part);
          part = fmaf(gelu_f(acc[mt][nt][1] + bb.y), sWg[c + 1], part);
          part = fmaf(gelu_f(acc[mt][nt][2] + bb.z), sWg[c + 2], part);
          part = fmaf(gelu_f(acc[mt][nt][3] + bb.w), sWg[c + 3], part);
        }
        part += __shfl_xor(part, 16, 64);
        part += __shfl_xor(part, 32, 64);
        if (lane < 16) atomicAdd(&gatelin[row], part);
      }
    } else {
      int bi[MT];
#pragma unroll
      for (int mt = 0; mt < MT; ++mt) {
        if (wc == 0) {
          float mv = -1e30f; int mi = 0;
#pragma unroll
          for (int nt = 0; nt < 4; ++nt)
#pragma unroll
            for (int j = 0; j < 4; ++j) {
              const int gc = nt * 16 + quad * 4 + j;
              const float v = acc[mt][nt][j];
              if (v > mv || (v == mv && gc < mi)) { mv = v; mi = gc; }
            }
#pragma unroll
          for (int off = 16; off <= 32; off <<= 1) {
            const float ov = __shfl_xor(mv, off, 64);
            const int oi = __shfl_xor(mi, off, 64);
            if (ov > mv || (ov == mv && oi < mi)) { mv = ov; mi = oi; }
          }
          bi[mt] = mi;
        } else {
          float mv = -1e30f; int mi = 0;
          if (quad < 2) {
#pragma unroll
            for (int j = 0; j < 4; ++j) {
              const int kc = quad * 4 + j;
              const float v = acc[mt][0][j];
              if (v > mv || (v == mv && kc < mi)) { mv = v; mi = kc; }
            }
          }
#pragma unroll
          for (int off = 16; off <= 32; off <<= 1) {
            const float ov = __shfl_xor(mv, off, 64);
            const int oi = __shfl_xor(mi, off, 64);
            if (ov > mv || (ov == mv && oi < mi)) { mv = ov; mi = oi; }
          }
          if (lane < 16) sKi[wr * MT * 16 + mt * 16 + l15] = mi;
        }
      }
      __syncthreads();
      if (wc == 0 && lane < 16) {
#pragma unroll
        for (int mt = 0; mt < MT; ++mt) {
          const int rl = wr * MT * 16 + mt * 16 + l15;
          const int row = m0 + rl;
          const int idx = bi[mt] * 8 + sKi[rl];
          const int b = row >> 12, tok = row & 4095;
          atomicOr(&bitmap[(size_t)(b * 512 + idx) * 64 + (tok >> 6)],
                   1ull << (tok & 63));
        }
      }
    }
  }
}

// ---------------------------------------------------------------------------
// pair: blocks [0,256) = G2' (incoming = H@Wm2 + sumg*bm2, f32)
//       blocks [256,1024) = qkv (Sb@Wqkvt + bqkv, bf16)
// ---------------------------------------------------------------------------
__global__ __launch_bounds__(256)
void gemm_pair_kernel(const bf16_t* __restrict__ H, const bf16_t* __restrict__ W2t,
                      const float* __restrict__ bm2, const float* __restrict__ sumg,
                      float* __restrict__ incom,
                      const bf16_t* __restrict__ Sb, const bf16_t* __restrict__ Wqkvt,
                      const float* __restrict__ bqkv, bf16_t* __restrict__ qkvb)
{
  int id = blockIdx.x;
  const bool first = id < 256;
  if (!first) id -= 256;
  const bf16_t* A  = first ? H : Sb;
  const bf16_t* Bt = first ? W2t : Wqkvt;
  const float* bias = first ? bm2 : bqkv;
  const int lda = first ? 512 : 256;
  const int K   = first ? 512 : 256;
  const int ldc = first ? 256 : 768;
  const int m0 = (id & 127) * 32;
  const int n0 = (id >> 7) * 128;
  const int t = threadIdx.x;
  const int w = t >> 6;
  const int lane = t & 63;
  const int wr = w >> 1, wc = w & 1;
  const int quad = lane >> 4, l15 = lane & 15;

  __shared__ bf16_t lA[32 * 32];
  __shared__ bf16_t lB[128 * 32];

  f32x4 acc[4];
#pragma unroll
  for (int nt = 0; nt < 4; ++nt) acc[nt] = (f32x4){0.f, 0.f, 0.f, 0.f};

  for (int k0 = 0; k0 < K; k0 += 32) {
    if (t < 128) {
      const int row = t >> 2, pp = t & 3;
      async16(A + (size_t)(m0 + row) * lda + k0 + (swz(row, pp) << 3),
              lA + (size_t)(t & 192) * 8);
    }
#pragma unroll
    for (int i = 0; i < 2; ++i) {
      const int c = i * 256 + t;
      const int row = c >> 2, pp = c & 3;
      async16(Bt + (size_t)(n0 + row) * K + k0 + (swz(row, pp) << 3),
              lB + (size_t)(i * 256 + (t & 192)) * 8);
    }
    __syncthreads();
    bf16x8 af, bfr[4];
    const int arow = wr * 16 + l15;
    af = *(const bf16x8*)&lA[arow * 32 + (swz(arow, quad) << 3)];
#pragma unroll
    for (int nt = 0; nt < 4; ++nt) {
      const int row = wc * 64 + nt * 16 + l15;
      bfr[nt] = *(const bf16x8*)&lB[row * 32 + (swz(row, quad) << 3)];
    }
#pragma unroll
    for (int nt = 0; nt < 4; ++nt)
      acc[nt] = __builtin_amdgcn_mfma_f32_16x16x32_bf16(bfr[nt], af, acc[nt], 0, 0, 0);
    __syncthreads();
  }

  const int row = m0 + wr * 16 + l15;
  if (first) {
    const float gt = sumg[row];
#pragma unroll
    for (int nt = 0; nt < 4; ++nt) {
      const int colb = n0 + wc * 64 + nt * 16 + quad * 4;
      const float4 bb = *(const float4*)&bias[colb];
      *(float4*)&incom[(size_t)row * ldc + colb] =
          make_float4(fmaf(gt, bb.x, acc[nt][0]), fmaf(gt, bb.y, acc[nt][1]),
                      fmaf(gt, bb.z, acc[nt][2]), fmaf(gt, bb.w, acc[nt][3]));
    }
  } else {
#pragma unroll
    for (int nt = 0; nt < 4; ++nt) {
      const int colb = n0 + wc * 64 + nt * 16 + quad * 4;
      const float4 bb = *(const float4*)&bias[colb];
      bf16x4v o; o[0]=(bf16_t)(acc[nt][0]+bb.x); o[1]=(bf16_t)(acc[nt][1]+bb.y);
      o[2]=(bf16_t)(acc[nt][2]+bb.z); o[3]=(bf16_t)(acc[nt][3]+bb.w);
      *(bf16x4v*)&qkvb[(size_t)row * ldc + colb] = o;
    }
  }
}

// ---------------------------------------------------------------------------
// gather: block per (b,slot); bitmap-driven; H = sum gate*gelu(h1) rows; sumg
// ---------------------------------------------------------------------------
__global__ __launch_bounds__(256)
void gather_kernel(const bf16_t* __restrict__ h1, const float* __restrict__ gatelin,
                   const float* __restrict__ bgt2, const u64* __restrict__ bitmap,
                   bf16_t* __restrict__ H, float* __restrict__ sumg)
{
  const int bs = blockIdx.x;
  const int b = bs >> 9;
  const int t = threadIdx.x;
  __shared__ u64 sw[64];
  if (t < 64) sw[t] = bitmap[(size_t)bs * 64 + t];
  __syncthreads();
  const float bg = bgt2[0];
  float a0 = 0.f, a1 = 0.f, sg = 0.f;
  for (int wd = 0; wd < 64; ++wd) {
    u64 word = sw[wd];
    while (word) {
      const int bit = __builtin_ctzll(word);
      word &= word - 1;
      const int l = (b << 12) + (wd << 6) + bit;
      const float g = 1.0f / (1.0f + __expf(-(gatelin[l] + bg)));
      const bf16x2v hv = *(const bf16x2v*)&h1[(size_t)l * 512 + t * 2];
      a0 = fmaf(g, gelu_f((float)hv[0]), a0);
      a1 = fmaf(g, gelu_f((float)hv[1]), a1);
      sg += g;
    }
  }
  bf16x2v o; o[0] = (bf16_t)a0; o[1] = (bf16_t)a1;
  *(bf16x2v*)&H[(size_t)bs * 512 + t * 2] = o;
  if (t == 0) sumg[bs] = sg;
}

// ---------------------------------------------------------------------------
// fused slot attention: block = (b, h, 32-query chunk)
// ---------------------------------------------------------------------------
__global__ __launch_bounds__(256)
void attn_kernel(const bf16_t* __restrict__ qkv, bf16_t* __restrict__ obuf)
{
  const int bid = blockIdx.x;
  const int qc = bid & 15;
  const int h = (bid >> 4) & 7;
  const int b = bid >> 7;
  const int t = threadIdx.x;
  const int w = t >> 6, lane = t & 63;
  const int quad = lane >> 4, l15 = lane & 15;

  __shared__ bf16_t sP[32 * 520];
  __shared__ bf16_t sVt[32 * 264];
  __shared__ float sL[32];

  bf16x8 qf[2];
#pragma unroll
  for (int mt = 0; mt < 2; ++mt) {
    const int row = b * 512 + qc * 32 + mt * 16 + l15;
    qf[mt] = *(const bf16x8*)&qkv[(size_t)row * 768 + h * 32 + quad * 8];
  }
  const float scale = 0.17677669529663687f;  // 1/sqrt(32)
  for (int kt = w; kt < 32; kt += 4) {
    const int key = b * 512 + kt * 16 + l15;
    const bf16x8 kf = *(const bf16x8*)&qkv[(size_t)key * 768 + 256 + h * 32 + quad * 8];
#pragma unroll
    for (int mt = 0; mt < 2; ++mt) {
      f32x4 c = (f32x4){0.f, 0.f, 0.f, 0.f};
      c = __builtin_amdgcn_mfma_f32_16x16x32_bf16(qf[mt], kf, c, 0, 0, 0);
#pragma unroll
      for (int r = 0; r < 4; ++r)
        sP[(mt * 16 + quad * 4 + r) * 520 + kt * 16 + l15] = (bf16_t)(c[r] * scale);
    }
  }
  __syncthreads();

#pragma unroll
  for (int ri = 0; ri < 8; ++ri) {
    const int row = w * 8 + ri;
    const bf16x8 sv = *(const bf16x8*)&sP[row * 520 + lane * 8];
    float sval[8];
    float mx = -1e30f;
#pragma unroll
    for (int j = 0; j < 8; ++j) { sval[j] = (float)sv[j]; mx = fmaxf(mx, sval[j]); }
#pragma unroll
    for (int off = 32; off; off >>= 1) mx = fmaxf(mx, __shfl_xor(mx, off, 64));
    float sum = 0.f;
    bf16x8 pv;
#pragma unroll
    for (int j = 0; j < 8; ++j) { const float e = __expf(sval[j] - mx); sum += e; pv[j] = (bf16_t)e; }
#pragma unroll
    for (int off = 32; off; off >>= 1) sum += __shfl_xor(sum, off, 64);
    *(bf16x8*)&sP[row * 520 + lane * 8] = pv;
    if (lane == 0) sL[row] = sum;
  }
  __syncthreads();

  const int omt = w >> 1, ont = w & 1;
  f32x4 oacc = (f32x4){0.f, 0.f, 0.f, 0.f};
  for (int half = 0; half < 2; ++half) {
    if (half) __syncthreads();
#pragma unroll
    for (int i = 0; i < 32; ++i) {
      const int el = i * 256 + t;
      const int dh = el & 31, key = el >> 5;
      sVt[dh * 264 + key] = qkv[(size_t)(b * 512 + half * 256 + key) * 768 + 512 + h * 32 + dh];
    }
    __syncthreads();
#pragma unroll
    for (int kt = 0; kt < 8; ++kt) {
      const bf16x8 af = *(const bf16x8*)&sP[(omt * 16 + l15) * 520 + half * 256 + kt * 32 + quad * 8];
      const bf16x8 vf = *(const bf16x8*)&sVt[(ont * 16 + l15) * 264 + kt * 32 + quad * 8];
      oacc = __builtin_amdgcn_mfma_f32_16x16x32_bf16(af, vf, oacc, 0, 0, 0);
    }
  }
#pragma unroll
  for (int r = 0; r < 4; ++r) {
    const int row = omt * 16 + quad * 4 + r;
    const float val = oacc[r] / sL[row];
    obuf[(size_t)(b * 512 + qc * 32 + row) * 256 + h * 32 + ont * 16 + l15] = (bf16_t)val;
  }
}

// ---------------------------------------------------------------------------
// slot_tail: per 16-row block, fully fused slot tail:
//   A: o2 = obuf@Wot + bo ; S1 = LN(S + o2)  (S1 kept in regs, packed to LDS)
//   B: U = gelu([S1|incom] @ Wu1t + bu1)     (A4 and U live in LDS)
//   C: out = LN(U @ Wu2t + bu2 + S1)
// ---------------------------------------------------------------------------
__global__ __launch_bounds__(256)
void slot_tail_kernel(const bf16_t* __restrict__ obuf, const bf16_t* __restrict__ Wot,
                      const float* __restrict__ bo, const float* __restrict__ S,
                      const float* __restrict__ incom,
                      const float* __restrict__ ag, const float* __restrict__ ab,
                      const bf16_t* __restrict__ Wu1t, const float* __restrict__ bu1,
                      const bf16_t* __restrict__ Wu2t, const float* __restrict__ bu2,
                      const float* __restrict__ lg, const float* __restrict__ lb,
                      float* __restrict__ out)
{
  const int m0 = blockIdx.x * 16;
  const int t = threadIdx.x;
  const int w = t >> 6, lane = t & 63;
  const int quad = lane >> 4, l15 = lane & 15;

  __shared__ bf16_t lB[512 * 32];      // 32 KB weight staging (max of stages)
  __shared__ bf16_t lA[16 * 32];       // 1 KB obuf tile
  __shared__ bf16_t sA[16 * 520];      // A4 then U (padded stride 520)
  __shared__ float sSum[4][16], sSq[4][16];

  // ---- stage A: Wo GEMM ----
  f32x4 acc[4];
#pragma unroll
  for (int nt = 0; nt < 4; ++nt) acc[nt] = (f32x4){0.f, 0.f, 0.f, 0.f};
  for (int k0 = 0; k0 < 256; k0 += 32) {
    if (t < 64) {
      const int row = t >> 2, pp = t & 3;
      async16(obuf + (size_t)(m0 + row) * 256 + k0 + (swz(row, pp) << 3), lA);
    }
#pragma unroll
    for (int i = 0; i < 4; ++i) {
      const int c = i * 256 + t;
      const int row = c >> 2, pp = c & 3;
      async16(Wot + (size_t)row * 256 + k0 + (swz(row, pp) << 3),
              lB + (size_t)(i * 256 + (t & 192)) * 8);
    }
    __syncthreads();
    const bf16x8 af = *(const bf16x8*)&lA[l15 * 32 + (swz(l15, quad) << 3)];
#pragma unroll
    for (int nt = 0; nt < 4; ++nt) {
      const int row = w * 64 + nt * 16 + l15;
      const bf16x8 bfr = *(const bf16x8*)&lB[row * 32 + (swz(row, quad) << 3)];
      acc[nt] = __builtin_amdgcn_mfma_f32_16x16x32_bf16(bfr, af, acc[nt], 0, 0, 0);
    }
    __syncthreads();
  }

  // ---- LN1 ----
  const int row = m0 + l15;
  float sum = 0.f, sq = 0.f;
#pragma unroll
  for (int nt = 0; nt < 4; ++nt) {
    const int colb = w * 64 + nt * 16 + quad * 4;
    const float4 bv = *(const float4*)&bo[colb];
    const float4 sv = *(const float4*)&S[(size_t)row * 256 + colb];
    float x0 = acc[nt][0] + bv.x + sv.x, x1 = acc[nt][1] + bv.y + sv.y;
    float x2 = acc[nt][2] + bv.z + sv.z, x3 = acc[nt][3] + bv.w + sv.w;
    acc[nt][0] = x0; acc[nt][1] = x1; acc[nt][2] = x2; acc[nt][3] = x3;
    sum += x0 + x1 + x2 + x3;
    sq += x0*x0 + x1*x1 + x2*x2 + x3*x3;
  }
  sum += __shfl_xor(sum, 16, 64); sum += __shfl_xor(sum, 32, 64);
  sq  += __shfl_xor(sq, 16, 64);  sq  += __shfl_xor(sq, 32, 64);
  if (lane < 16) { sSum[w][l15] = sum; sSq[w][l15] = sq; }
  __syncthreads();
  {
    const float tot = sSum[0][l15] + sSum[1][l15] + sSum[2][l15] + sSum[3][l15];
    const float tq  = sSq[0][l15] + sSq[1][l15] + sSq[2][l15] + sSq[3][l15];
    const float mean = tot * 0.00390625f;
    const float var = tq * 0.00390625f - mean * mean;
    const float rstd = rsqrtf(var + LN_EPS);
#pragma unroll
    for (int nt = 0; nt < 4; ++nt) {
      const int colb = w * 64 + nt * 16 + quad * 4;
      const float4 gg = *(const float4*)&ag[colb];
      const float4 bv = *(const float4*)&ab[colb];
      acc[nt][0] = (acc[nt][0]-mean)*rstd*gg.x + bv.x;
      acc[nt][1] = (acc[nt][1]-mean)*rstd*gg.y + bv.y;
      acc[nt][2] = (acc[nt][2]-mean)*rstd*gg.z + bv.z;
      acc[nt][3] = (acc[nt][3]-mean)*rstd*gg.w + bv.w;
      bf16x4v yb; yb[0]=(bf16_t)acc[nt][0]; yb[1]=(bf16_t)acc[nt][1];
      yb[2]=(bf16_t)acc[nt][2]; yb[3]=(bf16_t)acc[nt][3];
      *(bf16x4v*)&sA[l15 * 520 + colb] = yb;
    }
  }
  // incom -> right half of A4
#pragma unroll
  for (int i = 0; i < 16; ++i) {
    const int idx = i * 256 + t;
    const int rr = idx >> 8, cc = idx & 255;
    sA[rr * 520 + 256 + cc] = (bf16_t)incom[(size_t)(m0 + rr) * 256 + cc];
  }
  // keep S1 in y regs (acc holds S1 now)
  float y[16];
#pragma unroll
  for (int nt = 0; nt < 4; ++nt)
#pragma unroll
    for (int j = 0; j < 4; ++j) y[nt * 4 + j] = acc[nt][j];
  __syncthreads();

  // ---- stage B: U = gelu(A4 @ Wu1t + bu1), 16 x 512 ----
  f32x4 acc2[8];
#pragma unroll
  for (int nt = 0; nt < 8; ++nt) acc2[nt] = (f32x4){0.f, 0.f, 0.f, 0.f};
  for (int k0 = 0; k0 < 512; k0 += 32) {
#pragma unroll
    for (int i = 0; i < 8; ++i) {
      const int c = i * 256 + t;
      const int rown = c >> 2, pp = c & 3;
      async16(Wu1t + (size_t)rown * 512 + k0 + (swz(rown, pp) << 3),
              lB + (size_t)(i * 256 + (t & 192)) * 8);
    }
    __syncthreads();
    const bf16x8 af = *(const bf16x8*)&sA[l15 * 520 + k0 + quad * 8];
#pragma unroll
    for (int nt = 0; nt < 8; ++nt) {
      const int rown = w * 128 + nt * 16 + l15;
      const bf16x8 bfr = *(const bf16x8*)&lB[rown * 32 + (swz(rown, quad) << 3)];
      acc2[nt] = __builtin_amdgcn_mfma_f32_16x16x32_bf16(bfr, af, acc2[nt], 0, 0, 0);
    }
    __syncthreads();
  }
  // gelu -> overwrite sA with U (all reads of A4 done: loop ended with barrier)
#pragma unroll
  for (int nt = 0; nt < 8; ++nt) {
    const int colb = w * 128 + nt * 16 + quad * 4;
    const float4 bv = *(const float4*)&bu1[colb];
    bf16x4v o;
    o[0] = (bf16_t)gelu_f(acc2[nt][0] + bv.x);
    o[1] = (bf16_t)gelu_f(acc2[nt][1] + bv.y);
    o[2] = (bf16_t)gelu_f(acc2[nt][2] + bv.z);
    o[3] = (bf16_t)gelu_f(acc2[nt][3] + bv.w);
    *(bf16x4v*)&sA[l15 * 520 + colb] = o;
  }
  __syncthreads();

  // ---- stage C: out = LN(U @ Wu2t + bu2 + S1) ----
  f32x4 acc3[4];
#pragma unroll
  for (int nt = 0; nt < 4; ++nt) acc3[nt] = (f32x4){0.f, 0.f, 0.f, 0.f};
  for (int k0 = 0; k0 < 512; k0 += 32) {
#pragma unroll
    for (int i = 0; i < 4; ++i) {
      const int c = i * 256 + t;
      const int rown = c >> 2, pp = c & 3;
      async16(Wu2t + (size_t)rown * 512 + k0 + (swz(rown, pp) << 3),
              lB + (size_t)(i * 256 + (t & 192)) * 8);
    }
    __syncthreads();
    const bf16x8 af = *(const bf16x8*)&sA[l15 * 520 + k0 + quad * 8];
#pragma unroll
    for (int nt = 0; nt < 4; ++nt) {
      const int rown = w * 64 + nt * 16 + l15;
      const bf16x8 bfr = *(const bf16x8*)&lB[rown * 32 + (swz(rown, quad) << 3)];
      acc3[nt] = __builtin_amdgcn_mfma_f32_16x16x32_bf16(bfr, af, acc3[nt], 0, 0, 0);
    }
    __syncthreads();
  }
  float sum2 = 0.f, sq2 = 0.f;
#pragma unroll
  for (int nt = 0; nt < 4; ++nt) {
    const int colb = w * 64 + nt * 16 + quad * 4;
    const float4 bv = *(const float4*)&bu2[colb];
    float x0 = acc3[nt][0] + bv.x + y[nt*4+0], x1 = acc3[nt][1] + bv.y + y[nt*4+1];
    float x2 = acc3[nt][2] + bv.z + y[nt*4+2], x3 = acc3[nt][3] + bv.w + y[nt*4+3];
    acc3[nt][0] = x0; acc3[nt][1] = x1; acc3[nt][2] = x2; acc3[nt][3] = x3;
    sum2 += x0 + x1 + x2 + x3;
    sq2 += x0*x0 + x1*x1 + x2*x2 + x3*x3;
  }
  sum2 += __shfl_xor(sum2, 16, 64); sum2 += __shfl_xor(sum2, 32, 64);
  sq2  += __shfl_xor(sq2, 16, 64);  sq2  += __shfl_xor(sq2, 32, 64);
  if (lane < 16) { sSum[w][l15] = sum2; sSq[w][l15] = sq2; }
  __syncthreads();
  const float tot2 = sSum[0][l15] + sSum[1][l15] + sSum[2][l15] + sSum[3][l15];
  const float tq2  = sSq[0][l15] + sSq[1][l15] + sSq[2][l15] + sSq[3][l15];
  const float mean2 = tot2 * 0.00390625f;
  const float var2 = tq2 * 0.00390625f - mean2 * mean2;
  const float rstd2 = rsqrtf(var2 + LN_EPS);
#pragma unroll
  for (int nt = 0; nt < 4; ++nt) {
    const int colb = w * 64 + nt * 16 + quad * 4;
    const float4 gg = *(const float4*)&lg[colb];
    const float4 bv = *(const float4*)&lb[colb];
    *(float4*)&out[(size_t)row * 256 + colb] = make_float4(
        (acc3[nt][0]-mean2)*rstd2*gg.x + bv.x, (acc3[nt][1]-mean2)*rstd2*gg.y + bv.y,
        (acc3[nt][2]-mean2)*rstd2*gg.z + bv.z, (acc3[nt][3]-mean2)*rstd2*gg.w + bv.w);
  }
}

// ---------------------------------------------------------------------------
extern "C" void kernel_launch(void* const* d_in, const int* in_sizes, int n_in,
                              void* d_out, int out_size, void* d_ws, size_t ws_size,
                              hipStream_t stream)
{
  (void)in_sizes; (void)n_in; (void)out_size; (void)ws_size;
  const float* X    = (const float*)d_in[0];
  const float* S    = (const float*)d_in[1];
  const float* Wg   = (const float*)d_in[2];
  const float* Wk   = (const float*)d_in[3];
  const float* Wm1  = (const float*)d_in[4];
  const float* bm1  = (const float*)d_in[5];
  const float* Wm2  = (const float*)d_in[6];
  const float* bm2  = (const float*)d_in[7];
  const float* Wgt1 = (const float*)d_in[8];
  const float* bgt1 = (const float*)d_in[9];
  const float* Wgt2 = (const float*)d_in[10];
  const float* bgt2 = (const float*)d_in[11];
  const float* Wqkv = (const float*)d_in[12];
  const float* bqkv = (const float*)d_in[13];
  const float* Wo   = (const float*)d_in[14];
  const float* bo   = (const float*)d_in[15];
  const float* alng = (const float*)d_in[16];
  const float* alnb = (const float*)d_in[17];
  const float* Wu1  = (const float*)d_in[18];
  const float* bu1  = (const float*)d_in[19];
  const float* Wu2  = (const float*)d_in[20];
  const float* bu2  = (const float*)d_in[21];
  const float* lng  = (const float*)d_in[22];
  const float* lnb  = (const float*)d_in[23];

  char* p = (char*)d_ws;
  auto carve = [&](size_t bytes) { char* r = p; p += bytes; return r; };
  bf16_t* Xb    = (bf16_t*)carve(16777216);   // 32768 x 256
  bf16_t* Sb    = (bf16_t*)carve(2097152);    // 4096 x 256
  bf16_t* W1t   = (bf16_t*)carve(458752);     // 896 x 256
  bf16_t* W2t   = (bf16_t*)carve(262144);     // 256 x 512
  bf16_t* Wqkvt = (bf16_t*)carve(393216);     // 768 x 256
  bf16_t* Wot   = (bf16_t*)carve(131072);     // 256 x 256
  bf16_t* Wu1t  = (bf16_t*)carve(524288);     // 512 x 512
  bf16_t* Wu2t  = (bf16_t*)carve(262144);     // 256 x 512
  bf16_t* h1    = (bf16_t*)carve(33554432);   // 32768 x 512 (raw msg pre-act)
  u64*    bitmap  = (u64*)carve(2097152);     // 4096 x 64 words (zeroed by prep)
  float*  gatelin = (float*)carve(131072);    // 32768 (zeroed by prep, adjacent)
  float*  incom = (float*)carve(4194304);     // 4096 x 256 f32
  bf16_t* qkvb  = (bf16_t*)carve(6291456);    // 4096 x 768
  bf16_t* obuf  = (bf16_t*)carve(2097152);    // 4096 x 256
  bf16_t* H     = (bf16_t*)carve(4194304);    // 4096 x 512
  float*  sumg  = (float*)carve(16384);

  // 1. prep (X, S, tiled weight transposes, zero bitmap+gatelin)
  prep_kernel<<<10005, 256, 0, stream>>>(X, S, Wg, Wk, Wm1, Wgt1, Wm2, Wqkv, Wo, Wu1, Wu2,
                                         Xb, Sb, W1t, W2t, Wqkvt, Wot, Wu1t, Wu2t,
                                         (float4*)bitmap);
  // 2. G1 + fused routing
  gemm_kernel<2,1><<<dim3(512,7), 256, 0, stream>>>(Xb, 256, W1t, 256, bm1, bgt1, h1, 512,
                                                    Wgt2, gatelin, bitmap);
  // 3. bitmap-driven aggregate (applies gelu)
  gather_kernel<<<4096, 256, 0, stream>>>(h1, gatelin, bgt2, bitmap, H, sumg);
  // 4. G2' (incoming) + qkv in one dispatch
  gemm_pair_kernel<<<1024, 256, 0, stream>>>(H, W2t, bm2, sumg, incom,
                                             Sb, Wqkvt, bqkv, qkvb);
  // 5. attention
  attn_kernel<<<1024, 256, 0, stream>>>(qkvb, obuf);
  // 6. fully fused slot tail -> d_out
  slot_tail_kernel<<<256, 256, 0, stream>>>(obuf, Wot, bo, S, incom, alng, alnb,
                                            Wu1t, bu1, Wu2t, bu2, lng, lnb,
                                            (float*)d_out);
}